// Round 1
// 518.140 us; speedup vs baseline: 1.0746x; 1.0746x over previous
//
#include <hip/hip_runtime.h>

// ============================================================================
// 2-layer LSTM cell + FF head, B=32768, IN=64, H=256, OUT=768.
//
// R3 structure: m97-style GEMMs (128x128 tile, BK=64, 4 waves, global_load_lds
// width-16 for BOTH operands, linear LDS) over pre-converted bf16 activations.
//
//   pack_all : bf16-convert inp / state1.out / state2.out into X buffers and
//              repack weights n-major bf16:
//                W1,W2: packed col n = 4*h + gate   (gate interleave -> a
//                       128-col N tile holds complete gate quadruples)
//                W3:    cols >=512 permuted n' = 512 + 4*t + m (softmax
//                       partners contiguous)
//   lstm_gemm<320,512> : X1[B,320] @ W1p -> fused cell update -> nstate1 f32
//                        + out1 bf16 into X2 cols 0..255
//   lstm_gemm<512,256> : X2[B,512] @ W2p -> nstate2 + out2 bf16 into X3
//   ff_gemm            : X3[B,256] @ W3p -> means | exp(dev) | softmax(mult)
//
// d_in order: 0 inp 1 state1 2 state2 | 3 l1_wf 4 l1_bf 5 l2_wf 6 l2_bf
//  7 l1_wk 8 l1_bk 9 l2_wk 10 l2_bk | 11 l1_wi 12 l1_bi 13 l2_wi 14 l2_bi
// 15 l1_ws 16 l1_bs 17 l2_ws 18 l2_bs | 19 ff_w[256,768]  (all f32)
//
// d_out (f32): means[B,256] | dev[B,256] | mult[B,256] | ns1[B,512] | ns2[B,512]
// ============================================================================

typedef __attribute__((ext_vector_type(8))) short short8;    // 8 bf16
typedef __attribute__((ext_vector_type(4))) short short4_t;  // 4 bf16 = 8 B
typedef __attribute__((ext_vector_type(4))) float floatx4;   // MFMA acc

#define BATCH 32768

static const size_t DEV_OFF  = (size_t)BATCH * 256;
static const size_t MULT_OFF = (size_t)2 * BATCH * 256;
static const size_t NS1_OFF  = (size_t)3 * BATCH * 256;
static const size_t NS2_OFF  = NS1_OFF + (size_t)BATCH * 512;

// workspace layout (ushort elements)
static const size_t W1P = 0;                                 // [1024][320]
static const size_t W2P = (size_t)1024 * 320;                // [1024][512]
static const size_t W3P = W2P + (size_t)1024 * 512;          // [768][256]
static const size_t X1O = W3P + (size_t)768 * 256;           // [B][320]
static const size_t X2O = X1O + (size_t)BATCH * 320;         // [B][512]
static const size_t X3O = X2O + (size_t)BATCH * 512;         // [B][256]

__device__ __forceinline__ unsigned short f2bf(float f) {
    union { float f; unsigned int i; } v; v.f = f;
    unsigned int i = v.i;
    i += 0x7fff + ((i >> 16) & 1);   // RNE
    return (unsigned short)(i >> 16);
}
__device__ __forceinline__ float sigmoidf_(float x) {
    return 1.f / (1.f + __expf(-x));
}
__device__ __forceinline__ float tanhf_(float x) {
    float e = __expf(2.f * x);       // inf-safe: x>>0 -> 1, x<<0 -> -1
    return 1.f - 2.f / (e + 1.f);
}

// async global->LDS, 16 B per lane; LDS dest = wave-uniform base + lane*16
__device__ __forceinline__ void gl_lds16(const unsigned short* g,
                                         unsigned short* l) {
    __builtin_amdgcn_global_load_lds(
        (const __attribute__((address_space(1))) unsigned int*)g,
        (__attribute__((address_space(3))) unsigned int*)l,
        16, 0, 0);
}

// ---------------------------------------------------------------------------
// pack_all: X conversions (float4 -> bf16x4) + weight repack.
// thread q regions (exactly 19456*256 threads):
//   [0,524288)          inp        -> X1 cols 0..63
//   [524288,2621440)    s1.out     -> X1 cols 64..319
//   [2621440,4718592)   s2.out     -> X2 cols 256..511
//   [4718592,4800512)   W1 repack  (n = 4h+g, k-major within n)
//   [4800512,4931584)   W2 repack
//   [4931584,4980736)   W3 repack  (mult third permuted)
// ---------------------------------------------------------------------------
__global__ __launch_bounds__(256) void pack_all(
    const float* __restrict__ inp, const float* __restrict__ s1,
    const float* __restrict__ s2,
    const float* __restrict__ w10, const float* __restrict__ w11,
    const float* __restrict__ w12, const float* __restrict__ w13,
    const float* __restrict__ w20, const float* __restrict__ w21,
    const float* __restrict__ w22, const float* __restrict__ w23,
    const float* __restrict__ fw, unsigned short* __restrict__ ws)
{
    const int q = blockIdx.x * 256 + threadIdx.x;
    if (q < 524288) {
        int r = q >> 4, c = (q & 15) << 2;
        float4 v = *(const float4*)(inp + (size_t)r * 64 + c);
        short4_t h;
        h.x = (short)f2bf(v.x); h.y = (short)f2bf(v.y);
        h.z = (short)f2bf(v.z); h.w = (short)f2bf(v.w);
        *(short4_t*)(ws + X1O + (size_t)r * 320 + c) = h;
    } else if (q < 2621440) {
        int j = q - 524288;
        int r = j >> 6, c = (j & 63) << 2;
        float4 v = *(const float4*)(s1 + (size_t)r * 512 + c);
        short4_t h;
        h.x = (short)f2bf(v.x); h.y = (short)f2bf(v.y);
        h.z = (short)f2bf(v.z); h.w = (short)f2bf(v.w);
        *(short4_t*)(ws + X1O + (size_t)r * 320 + 64 + c) = h;
    } else if (q < 4718592) {
        int j = q - 2621440;
        int r = j >> 6, c = (j & 63) << 2;
        float4 v = *(const float4*)(s2 + (size_t)r * 512 + c);
        short4_t h;
        h.x = (short)f2bf(v.x); h.y = (short)f2bf(v.y);
        h.z = (short)f2bf(v.z); h.w = (short)f2bf(v.w);
        *(short4_t*)(ws + X2O + (size_t)r * 512 + 256 + c) = h;
    } else if (q < 4800512) {
        int j = q - 4718592;
        int n = j / 80, k = (j % 80) << 2;
        int h = n >> 2, g = n & 3;
        const float* s = g == 0 ? w10 : g == 1 ? w11 : g == 2 ? w12 : w13;
        short4_t o;
        o.x = (short)f2bf(s[(size_t)(k + 0) * 256 + h]);
        o.y = (short)f2bf(s[(size_t)(k + 1) * 256 + h]);
        o.z = (short)f2bf(s[(size_t)(k + 2) * 256 + h]);
        o.w = (short)f2bf(s[(size_t)(k + 3) * 256 + h]);
        *(short4_t*)(ws + W1P + (size_t)n * 320 + k) = o;
    } else if (q < 4931584) {
        int j = q - 4800512;
        int n = j >> 7, k = (j & 127) << 2;
        int h = n >> 2, g = n & 3;
        const float* s = g == 0 ? w20 : g == 1 ? w21 : g == 2 ? w22 : w23;
        short4_t o;
        o.x = (short)f2bf(s[(size_t)(k + 0) * 256 + h]);
        o.y = (short)f2bf(s[(size_t)(k + 1) * 256 + h]);
        o.z = (short)f2bf(s[(size_t)(k + 2) * 256 + h]);
        o.w = (short)f2bf(s[(size_t)(k + 3) * 256 + h]);
        *(short4_t*)(ws + W2P + (size_t)n * 512 + k) = o;
    } else {
        int j = q - 4931584;
        int n = j >> 6, k = (j & 63) << 2;
        // mult third permuted so softmax partners (m=0..3, fixed t) are the
        // 4 contiguous packed cols 512 + 4t + m
        int col = (n < 512) ? n : (512 + ((n & 3) << 6) + ((n - 512) >> 2));
        short4_t o;
        o.x = (short)f2bf(fw[(size_t)(k + 0) * 768 + col]);
        o.y = (short)f2bf(fw[(size_t)(k + 1) * 768 + col]);
        o.z = (short)f2bf(fw[(size_t)(k + 2) * 768 + col]);
        o.w = (short)f2bf(fw[(size_t)(k + 3) * 768 + col]);
        *(short4_t*)(ws + W3P + (size_t)n * 256 + k) = o;
    }
}

// ---------------------------------------------------------------------------
// LSTM GEMM+cell: 128x128 tile, BK=64, 4 waves (2x2 of 64x64), m97 staging.
// Packed N col n = 4h+g; grid (8 n-tiles, 256 row-tiles).
// Epilogue: 2 passes of 64 packed cols (16 h) through reused LDS (f32),
// fused sigmoid/tanh cell update; writes out|cell f32 + out bf16 to xnext.
// ---------------------------------------------------------------------------
template<int KT, int XST>
__global__ __launch_bounds__(256) void lstm_gemm(
    const unsigned short* __restrict__ xin,   // [B][KT] bf16
    const unsigned short* __restrict__ wp,    // [1024][KT] bf16, n = 4h+g
    const float* __restrict__ b0, const float* __restrict__ b1,
    const float* __restrict__ b2, const float* __restrict__ b3,
    const float* __restrict__ state,          // [B][512] f32 (cell at +256)
    float* __restrict__ nstate,               // [B][512] f32
    unsigned short* __restrict__ xnext)       // [B][XST] bf16, cols 0..255
{
    __shared__ __align__(16) union {
        struct { unsigned short a[128][64]; unsigned short b[128][64]; } st;
        float ep[128][68];                    // padded: stride 68 f32
    } lds;
    __shared__ float sbias[4][32];

    const int tid  = threadIdx.x;
    const int w    = tid >> 6;
    const int lane = tid & 63;
    const int lhi  = lane >> 4, llo = lane & 15;
    const int wr   = w >> 1, wc = w & 1;
    const int nt   = blockIdx.x;              // n-tile (0..7)
    const int row0 = blockIdx.y * 128;
    const int nc0  = nt * 128;
    const int hbase = nt * 32;

    if (tid < 128) {
        int g = tid >> 5, hl = tid & 31;
        const float* bp = g == 0 ? b0 : g == 1 ? b1 : g == 2 ? b2 : b3;
        sbias[g][hl] = bp[hbase + hl];
    }

    floatx4 acc[4][4];
#pragma unroll
    for (int i = 0; i < 4; i++)
#pragma unroll
        for (int j = 0; j < 4; j++) acc[i][j] = (floatx4){0.f, 0.f, 0.f, 0.f};

    const int arow  = (w << 5) + (lane >> 3);     // wave stages 32 rows
    const int acolb = (lane & 7) << 3;            // ushort offset
    const unsigned short* agp = xin + (size_t)(row0 + arow) * KT + acolb;
    const unsigned short* bgp = wp  + (size_t)(nc0 + arow) * KT + acolb;

    for (int c = 0; c < KT / 64; ++c) {
        const int kb = c << 6;
#pragma unroll
        for (int p = 0; p < 4; ++p) {
            gl_lds16(agp + (size_t)(p * 8) * KT + kb,
                     &lds.st.a[(w << 5) + (p << 3)][0]);
            gl_lds16(bgp + (size_t)(p * 8) * KT + kb,
                     &lds.st.b[(w << 5) + (p << 3)][0]);
        }
        __syncthreads();
#pragma unroll
        for (int ks = 0; ks < 2; ++ks) {
            const int k8 = ks * 32 + lhi * 8;
            short8 a[4], b[4];
#pragma unroll
            for (int mi = 0; mi < 4; mi++)
                a[mi] = *(const short8*)&lds.st.a[wr * 64 + mi * 16 + llo][k8];
#pragma unroll
            for (int ni = 0; ni < 4; ni++)
                b[ni] = *(const short8*)&lds.st.b[wc * 64 + ni * 16 + llo][k8];
#pragma unroll
            for (int mi = 0; mi < 4; mi++)
#pragma unroll
                for (int ni = 0; ni < 4; ni++)
                    acc[mi][ni] = __builtin_amdgcn_mfma_f32_16x16x32_bf16(
                        a[mi], b[ni], acc[mi][ni], 0, 0, 0);
        }
        __syncthreads();
    }

    // ---- fused cell update: 2 passes of 64 packed cols (16 h each) ----
    for (int pass = 0; pass < 2; ++pass) {
        if (pass) __syncthreads();
        if (wc == pass) {
#pragma unroll
            for (int mi = 0; mi < 4; mi++)
#pragma unroll
                for (int ni = 0; ni < 4; ni++)
#pragma unroll
                    for (int r = 0; r < 4; r++)
                        lds.ep[wr * 64 + mi * 16 + lhi * 4 + r]
                              [ni * 16 + llo] = acc[mi][ni][r];
        }
        __syncthreads();
        const int hl   = tid & 15;
        const int hblk = pass * 16 + hl;
        const int hg   = hbase + hblk;
        const float bf_ = sbias[0][hblk], bk_ = sbias[1][hblk];
        const float bi_ = sbias[2][hblk], bs_ = sbias[3][hblk];
#pragma unroll
        for (int rr = 0; rr < 8; ++rr) {
            const int r = (tid >> 4) + rr * 16;
            float4 z = *(const float4*)&lds.ep[r][hl << 2];
            float rst = sigmoidf_(z.x + bf_);
            float wrt = sigmoidf_(z.y + bk_);
            float itm = tanhf_(z.z + bi_);
            float rd  = sigmoidf_(z.w + bs_);
            const size_t rowel = (size_t)(row0 + r) * 512;
            float cold = state[rowel + 256 + hg];
            float cell = rst * cold + wrt * itm;
            float o = rd * tanhf_(cell);
            nstate[rowel + hg]       = o;
            nstate[rowel + 256 + hg] = cell;
            xnext[(size_t)(row0 + r) * XST + hg] = f2bf(o);
        }
    }
}

// ---------------------------------------------------------------------------
// FF head GEMM: X3[B,256] @ W3p[768,256]; grid (6 n-tiles, 256 row-tiles).
//   nt 0,1 -> means (identity)   nt 2,3 -> deviances (exp)
//   nt 4,5 -> mult (softmax over 4 contiguous packed cols per t)
// ---------------------------------------------------------------------------
__global__ __launch_bounds__(256) void ff_gemm(
    const unsigned short* __restrict__ xin,   // [B][256] bf16
    const unsigned short* __restrict__ wp,    // [768][256] bf16 packed
    float* __restrict__ out)
{
    __shared__ __align__(16) union {
        struct { unsigned short a[128][64]; unsigned short b[128][64]; } st;
        float ep[128][68];
    } lds;

    const int tid  = threadIdx.x;
    const int w    = tid >> 6;
    const int lane = tid & 63;
    const int lhi  = lane >> 4, llo = lane & 15;
    const int wr   = w >> 1, wc = w & 1;
    const int nt   = blockIdx.x;              // 0..5
    const int row0 = blockIdx.y * 128;
    const int nc0  = nt * 128;

    floatx4 acc[4][4];
#pragma unroll
    for (int i = 0; i < 4; i++)
#pragma unroll
        for (int j = 0; j < 4; j++) acc[i][j] = (floatx4){0.f, 0.f, 0.f, 0.f};

    const int arow  = (w << 5) + (lane >> 3);
    const int acolb = (lane & 7) << 3;
    const unsigned short* agp = xin + (size_t)(row0 + arow) * 256 + acolb;
    const unsigned short* bgp = wp  + (size_t)(nc0 + arow) * 256 + acolb;

    for (int c = 0; c < 4; ++c) {
        const int kb = c << 6;
#pragma unroll
        for (int p = 0; p < 4; ++p) {
            gl_lds16(agp + (size_t)(p * 8) * 256 + kb,
                     &lds.st.a[(w << 5) + (p << 3)][0]);
            gl_lds16(bgp + (size_t)(p * 8) * 256 + kb,
                     &lds.st.b[(w << 5) + (p << 3)][0]);
        }
        __syncthreads();
#pragma unroll
        for (int ks = 0; ks < 2; ++ks) {
            const int k8 = ks * 32 + lhi * 8;
            short8 a[4], b[4];
#pragma unroll
            for (int mi = 0; mi < 4; mi++)
                a[mi] = *(const short8*)&lds.st.a[wr * 64 + mi * 16 + llo][k8];
#pragma unroll
            for (int ni = 0; ni < 4; ni++)
                b[ni] = *(const short8*)&lds.st.b[wc * 64 + ni * 16 + llo][k8];
#pragma unroll
            for (int mi = 0; mi < 4; mi++)
#pragma unroll
                for (int ni = 0; ni < 4; ni++)
                    acc[mi][ni] = __builtin_amdgcn_mfma_f32_16x16x32_bf16(
                        a[mi], b[ni], acc[mi][ni], 0, 0, 0);
        }
        __syncthreads();
    }

    if (nt < 4) {
        const bool dev = (nt >= 2);
        float* obase = out + (dev ? DEV_OFF : (size_t)0);
        const int cb = (nt & 1) * 128 + wc * 64;
#pragma unroll
        for (int mi = 0; mi < 4; mi++)
#pragma unroll
            for (int ni = 0; ni < 4; ni++) {
                const int cc = cb + ni * 16 + llo;
#pragma unroll
                for (int r = 0; r < 4; r++) {
                    const int m = wr * 64 + mi * 16 + lhi * 4 + r;
                    float v = acc[mi][ni][r];
                    if (dev) v = __expf(v);
                    obase[(size_t)(row0 + m) * 256 + cc] = v;
                }
            }
    } else {
        // mult: packed col 512 + 4t + m; softmax over the 4 contiguous m
        const int tb = (nt - 4) * 32;
        for (int pass = 0; pass < 2; ++pass) {
            if (pass) __syncthreads();
            if (wc == pass) {
#pragma unroll
                for (int mi = 0; mi < 4; mi++)
#pragma unroll
                    for (int ni = 0; ni < 4; ni++)
#pragma unroll
                        for (int r = 0; r < 4; r++)
                            lds.ep[wr * 64 + mi * 16 + lhi * 4 + r]
                                  [ni * 16 + llo] = acc[mi][ni][r];
            }
            __syncthreads();
            const int tl = tid & 15;
#pragma unroll
            for (int rr = 0; rr < 8; ++rr) {
                const int r = (tid >> 4) + rr * 16;
                float4 z = *(const float4*)&lds.ep[r][tl << 2];
                float mx = fmaxf(fmaxf(z.x, z.y), fmaxf(z.z, z.w));
                float e0 = __expf(z.x - mx), e1 = __expf(z.y - mx);
                float e2 = __expf(z.z - mx), e3 = __expf(z.w - mx);
                float inv = 1.f / (e0 + e1 + e2 + e3);
                size_t base = MULT_OFF + (size_t)(row0 + r) * 256
                            + tb + pass * 16 + tl;
                out[base]       = e0 * inv;
                out[base + 64]  = e1 * inv;
                out[base + 128] = e2 * inv;
                out[base + 192] = e3 * inv;
            }
        }
    }
}

// ---------------------------------------------------------------------------
extern "C" void kernel_launch(void* const* d_in, const int* in_sizes, int n_in,
                              void* d_out, int out_size, void* d_ws, size_t ws_size,
                              hipStream_t stream)
{
    typedef const float* cfp;
    cfp inp = (cfp)d_in[0];
    cfp st1 = (cfp)d_in[1];
    cfp st2 = (cfp)d_in[2];
    cfp l1w0 = (cfp)d_in[3],  l1w1 = (cfp)d_in[7],  l1w2 = (cfp)d_in[11], l1w3 = (cfp)d_in[15];
    cfp l1b0 = (cfp)d_in[4],  l1b1 = (cfp)d_in[8],  l1b2 = (cfp)d_in[12], l1b3 = (cfp)d_in[16];
    cfp l2w0 = (cfp)d_in[5],  l2w1 = (cfp)d_in[9],  l2w2 = (cfp)d_in[13], l2w3 = (cfp)d_in[17];
    cfp l2b0 = (cfp)d_in[6],  l2b1 = (cfp)d_in[10], l2b2 = (cfp)d_in[14], l2b3 = (cfp)d_in[18];
    cfp ffw = (cfp)d_in[19];

    float* out = (float*)d_out;
    unsigned short* ws = (unsigned short*)d_ws;

    // pack + convert: 4,980,736 quad-element threads = 19456 blocks
    pack_all<<<19456, 256, 0, stream>>>(inp, st1, st2,
                                        l1w0, l1w1, l1w2, l1w3,
                                        l2w0, l2w1, l2w2, l2w3, ffw, ws);

    // layer 1: X1[B,320] @ W1p -> nstate1 (f32) + out1 bf16 -> X2 cols 0..255
    lstm_gemm<320, 512><<<dim3(8, 256), 256, 0, stream>>>(
        ws + X1O, ws + W1P, l1b0, l1b1, l1b2, l1b3,
        st1, out + NS1_OFF, ws + X2O);

    // layer 2: X2[B,512] @ W2p -> nstate2 (f32) + out2 bf16 -> X3
    lstm_gemm<512, 256><<<dim3(8, 256), 256, 0, stream>>>(
        ws + X2O, ws + W2P, l2b0, l2b1, l2b2, l2b3,
        st2, out + NS2_OFF, ws + X3O);

    // FF head + fused epilogues
    ff_gemm<<<dim3(6, 256), 256, 0, stream>>>(ws + X3O, ws + W3P, out);
}

// Round 2
// 506.263 us; speedup vs baseline: 1.0998x; 1.0235x over previous
//
#include <hip/hip_runtime.h>

// ============================================================================
// 2-layer LSTM cell + FF head, B=32768, IN=64, H=256, OUT=768.
//
// R4 structure: m97-style GEMMs (128x128 tile, BK=64, 4 waves, global_load_lds
// width-16 for BOTH operands, linear LDS) over pre-converted bf16 activations,
// with REGISTER-ONLY epilogues:
//   - W1/W2 packed col  c = (h>>4)*64 + g*16 + (h&15)   -> the 4 gates of one
//     h live in acc[mi][0..3][r] of a single lane (ni dimension = gate).
//   - W3 mult third     c = 512 + (t>>4)*64 + m*16 + (t&15) -> the 4 softmax
//     partners live in the ni dimension. No epilogue LDS pass, no extra syncs.
//   - XCD-aware block remap: XCD (lin&7) owns row-tiles [xcd*32, xcd*32+32),
//     nt cycles fastest -> A-tile is re-read 8x from the SAME L2.
//
// d_in order: 0 inp 1 state1 2 state2 | 3 l1_wf 4 l1_bf 5 l2_wf 6 l2_bf
//  7 l1_wk 8 l1_bk 9 l2_wk 10 l2_bk | 11 l1_wi 12 l1_bi 13 l2_wi 14 l2_bi
// 15 l1_ws 16 l1_bs 17 l2_ws 18 l2_bs | 19 ff_w[256,768]  (all f32)
//
// d_out (f32): means[B,256] | dev[B,256] | mult[B,256] | ns1[B,512] | ns2[B,512]
// ============================================================================

typedef __attribute__((ext_vector_type(8))) short short8;    // 8 bf16
typedef __attribute__((ext_vector_type(4))) short short4_t;  // 4 bf16 = 8 B
typedef __attribute__((ext_vector_type(4))) float floatx4;   // MFMA acc

#define BATCH 32768

static const size_t DEV_OFF  = (size_t)BATCH * 256;
static const size_t MULT_OFF = (size_t)2 * BATCH * 256;
static const size_t NS1_OFF  = (size_t)3 * BATCH * 256;
static const size_t NS2_OFF  = NS1_OFF + (size_t)BATCH * 512;

// workspace layout (ushort elements)
static const size_t W1P = 0;                                 // [1024][320]
static const size_t W2P = (size_t)1024 * 320;                // [1024][512]
static const size_t W3P = W2P + (size_t)1024 * 512;          // [768][256]
static const size_t X1O = W3P + (size_t)768 * 256;           // [B][320]
static const size_t X2O = X1O + (size_t)BATCH * 320;         // [B][512]
static const size_t X3O = X2O + (size_t)BATCH * 512;         // [B][256]

__device__ __forceinline__ unsigned short f2bf(float f) {
    union { float f; unsigned int i; } v; v.f = f;
    unsigned int i = v.i;
    i += 0x7fff + ((i >> 16) & 1);   // RNE
    return (unsigned short)(i >> 16);
}
__device__ __forceinline__ float sigmoidf_(float x) {
    return 1.f / (1.f + __expf(-x));
}
__device__ __forceinline__ float tanhf_(float x) {
    float e = __expf(2.f * x);       // inf-safe: x>>0 -> 1, x<<0 -> -1
    return 1.f - 2.f / (e + 1.f);
}

// async global->LDS, 16 B per lane; LDS dest = wave-uniform base + lane*16
__device__ __forceinline__ void gl_lds16(const unsigned short* g,
                                         unsigned short* l) {
    __builtin_amdgcn_global_load_lds(
        (const __attribute__((address_space(1))) unsigned int*)g,
        (__attribute__((address_space(3))) unsigned int*)l,
        16, 0, 0);
}

// ---------------------------------------------------------------------------
// pack_all: X conversions (float4 -> bf16x4) + weight repack.
// thread q regions (exactly 19456*256 threads):
//   [0,524288)          inp        -> X1 cols 0..63
//   [524288,2621440)    s1.out     -> X1 cols 64..319
//   [2621440,4718592)   s2.out     -> X2 cols 256..511
//   [4718592,4800512)   W1 repack  (c = (h>>4)*64 + g*16 + (h&15))
//   [4800512,4931584)   W2 repack  (same col mapping)
//   [4931584,4980736)   W3 repack  (mult third: c = 512+(t>>4)*64+m*16+(t&15))
// ---------------------------------------------------------------------------
__global__ __launch_bounds__(256) void pack_all(
    const float* __restrict__ inp, const float* __restrict__ s1,
    const float* __restrict__ s2,
    const float* __restrict__ w10, const float* __restrict__ w11,
    const float* __restrict__ w12, const float* __restrict__ w13,
    const float* __restrict__ w20, const float* __restrict__ w21,
    const float* __restrict__ w22, const float* __restrict__ w23,
    const float* __restrict__ fw, unsigned short* __restrict__ ws)
{
    const int q = blockIdx.x * 256 + threadIdx.x;
    if (q < 524288) {
        int r = q >> 4, c = (q & 15) << 2;
        float4 v = *(const float4*)(inp + (size_t)r * 64 + c);
        short4_t h;
        h.x = (short)f2bf(v.x); h.y = (short)f2bf(v.y);
        h.z = (short)f2bf(v.z); h.w = (short)f2bf(v.w);
        *(short4_t*)(ws + X1O + (size_t)r * 320 + c) = h;
    } else if (q < 2621440) {
        int j = q - 524288;
        int r = j >> 6, c = (j & 63) << 2;
        float4 v = *(const float4*)(s1 + (size_t)r * 512 + c);
        short4_t h;
        h.x = (short)f2bf(v.x); h.y = (short)f2bf(v.y);
        h.z = (short)f2bf(v.z); h.w = (short)f2bf(v.w);
        *(short4_t*)(ws + X1O + (size_t)r * 320 + 64 + c) = h;
    } else if (q < 4718592) {
        int j = q - 2621440;
        int r = j >> 6, c = (j & 63) << 2;
        float4 v = *(const float4*)(s2 + (size_t)r * 512 + c);
        short4_t h;
        h.x = (short)f2bf(v.x); h.y = (short)f2bf(v.y);
        h.z = (short)f2bf(v.z); h.w = (short)f2bf(v.w);
        *(short4_t*)(ws + X2O + (size_t)r * 512 + 256 + c) = h;
    } else if (q < 4800512) {
        int j = q - 4718592;
        int n = j / 80, k = (j % 80) << 2;          // n = packed col
        int hh = ((n >> 6) << 4) + (n & 15);        // h
        int g = (n >> 4) & 3;                       // gate
        const float* s = g == 0 ? w10 : g == 1 ? w11 : g == 2 ? w12 : w13;
        short4_t o;
        o.x = (short)f2bf(s[(size_t)(k + 0) * 256 + hh]);
        o.y = (short)f2bf(s[(size_t)(k + 1) * 256 + hh]);
        o.z = (short)f2bf(s[(size_t)(k + 2) * 256 + hh]);
        o.w = (short)f2bf(s[(size_t)(k + 3) * 256 + hh]);
        *(short4_t*)(ws + W1P + (size_t)n * 320 + k) = o;
    } else if (q < 4931584) {
        int j = q - 4800512;
        int n = j >> 7, k = (j & 127) << 2;
        int hh = ((n >> 6) << 4) + (n & 15);
        int g = (n >> 4) & 3;
        const float* s = g == 0 ? w20 : g == 1 ? w21 : g == 2 ? w22 : w23;
        short4_t o;
        o.x = (short)f2bf(s[(size_t)(k + 0) * 256 + hh]);
        o.y = (short)f2bf(s[(size_t)(k + 1) * 256 + hh]);
        o.z = (short)f2bf(s[(size_t)(k + 2) * 256 + hh]);
        o.w = (short)f2bf(s[(size_t)(k + 3) * 256 + hh]);
        *(short4_t*)(ws + W2P + (size_t)n * 512 + k) = o;
    } else {
        int j = q - 4931584;
        int n = j >> 6, k = (j & 63) << 2;
        int col;
        if (n < 512) col = n;                       // means | deviances
        else {                                      // mult third, partner-in-ni
            int t = (((n - 512) >> 6) << 4) + (n & 15);
            int m = (n >> 4) & 3;
            col = 512 + m * 64 + t;
        }
        short4_t o;
        o.x = (short)f2bf(fw[(size_t)(k + 0) * 768 + col]);
        o.y = (short)f2bf(fw[(size_t)(k + 1) * 768 + col]);
        o.z = (short)f2bf(fw[(size_t)(k + 2) * 768 + col]);
        o.w = (short)f2bf(fw[(size_t)(k + 3) * 768 + col]);
        *(short4_t*)(ws + W3P + (size_t)n * 256 + k) = o;
    }
}

// ---------------------------------------------------------------------------
// LSTM GEMM+cell: 128x128 tile, BK=64, 4 waves (2x2 of 64x64), m97 staging.
// Grid 2048 1D, XCD-remapped: xcd = lin&7 owns rows [xcd*32,+32), nt fastest.
// Wave lane holds gates f,k,i,s of h = nt*32 + wc*16 + llo in acc[mi][0..3][r];
// register-only cell update, no epilogue LDS pass.
// ---------------------------------------------------------------------------
template<int KT, int XST>
__global__ __launch_bounds__(256) void lstm_gemm(
    const unsigned short* __restrict__ xin,   // [B][KT] bf16
    const unsigned short* __restrict__ wp,    // [1024][KT] bf16 packed cols
    const float* __restrict__ b0, const float* __restrict__ b1,
    const float* __restrict__ b2, const float* __restrict__ b3,
    const float* __restrict__ state,          // [B][512] f32 (cell at +256)
    float* __restrict__ nstate,               // [B][512] f32
    unsigned short* __restrict__ xnext)       // [B][XST] bf16, cols 0..255
{
    __shared__ __align__(16) struct {
        unsigned short a[128][64];
        unsigned short b[128][64];
    } lds;

    const int tid  = threadIdx.x;
    const int w    = tid >> 6;
    const int lane = tid & 63;
    const int lhi  = lane >> 4, llo = lane & 15;
    const int wr   = w >> 1, wc = w & 1;

    // XCD-aware remap: same A-tile consumed by 8 consecutive same-XCD blocks
    const int lin  = blockIdx.x;
    const int xcd  = lin & 7;
    const int kk   = lin >> 3;
    const int nt   = kk & 7;
    const int row0 = (xcd * 32 + (kk >> 3)) * 128;
    const int nc0  = nt * 128;

    floatx4 acc[4][4];
#pragma unroll
    for (int i = 0; i < 4; i++)
#pragma unroll
        for (int j = 0; j < 4; j++) acc[i][j] = (floatx4){0.f, 0.f, 0.f, 0.f};

    const int arow  = (w << 5) + (lane >> 3);     // wave stages 32 rows
    const int acolb = (lane & 7) << 3;            // ushort offset
    const unsigned short* agp = xin + (size_t)(row0 + arow) * KT + acolb;
    const unsigned short* bgp = wp  + (size_t)(nc0 + arow) * KT + acolb;

    for (int c = 0; c < KT / 64; ++c) {
        const int kb = c << 6;
#pragma unroll
        for (int p = 0; p < 4; ++p) {
            gl_lds16(agp + (size_t)(p * 8) * KT + kb,
                     &lds.a[(w << 5) + (p << 3)][0]);
            gl_lds16(bgp + (size_t)(p * 8) * KT + kb,
                     &lds.b[(w << 5) + (p << 3)][0]);
        }
        __syncthreads();
#pragma unroll
        for (int ks = 0; ks < 2; ++ks) {
            const int k8 = ks * 32 + lhi * 8;
            short8 a[4], b[4];
#pragma unroll
            for (int mi = 0; mi < 4; mi++)
                a[mi] = *(const short8*)&lds.a[wr * 64 + mi * 16 + llo][k8];
#pragma unroll
            for (int ni = 0; ni < 4; ni++)
                b[ni] = *(const short8*)&lds.b[wc * 64 + ni * 16 + llo][k8];
#pragma unroll
            for (int mi = 0; mi < 4; mi++)
#pragma unroll
                for (int ni = 0; ni < 4; ni++)
                    acc[mi][ni] = __builtin_amdgcn_mfma_f32_16x16x32_bf16(
                        a[mi], b[ni], acc[mi][ni], 0, 0, 0);
        }
        __syncthreads();
    }

    // ---- register-only cell update: lane owns h = nt*32 + wc*16 + llo ----
    const int h = nt * 32 + wc * 16 + llo;
    const float bf_ = b0[h], bk_ = b1[h], bi_ = b2[h], bs_ = b3[h];
#pragma unroll
    for (int mi = 0; mi < 4; mi++)
#pragma unroll
        for (int r = 0; r < 4; r++) {
            const int m = wr * 64 + mi * 16 + lhi * 4 + r;
            const size_t rowel = (size_t)(row0 + m) * 512;
            float rst = sigmoidf_(acc[mi][0][r] + bf_);
            float wrt = sigmoidf_(acc[mi][1][r] + bk_);
            float itm = tanhf_(acc[mi][2][r] + bi_);
            float rd  = sigmoidf_(acc[mi][3][r] + bs_);
            float cold = state[rowel + 256 + h];
            float cell = rst * cold + wrt * itm;
            float o = rd * tanhf_(cell);
            nstate[rowel + h]       = o;
            nstate[rowel + 256 + h] = cell;
            xnext[(size_t)(row0 + m) * XST + h] = f2bf(o);
        }
}

// ---------------------------------------------------------------------------
// FF head GEMM: X3[B,256] @ W3p[768,256]; grid 1536 1D, XCD-remapped.
//   nt 0,1 -> means (identity)   nt 2,3 -> deviances (exp)
//   nt 4,5 -> mult: softmax partners in ni dimension, register-only.
// ---------------------------------------------------------------------------
__global__ __launch_bounds__(256) void ff_gemm(
    const unsigned short* __restrict__ xin,   // [B][256] bf16
    const unsigned short* __restrict__ wp,    // [768][256] bf16 packed
    float* __restrict__ out)
{
    __shared__ __align__(16) struct {
        unsigned short a[128][64];
        unsigned short b[128][64];
    } lds;

    const int tid  = threadIdx.x;
    const int w    = tid >> 6;
    const int lane = tid & 63;
    const int lhi  = lane >> 4, llo = lane & 15;
    const int wr   = w >> 1, wc = w & 1;

    const int lin  = blockIdx.x;
    const int xcd  = lin & 7;
    const int kk   = lin >> 3;                // [0,192)
    const int nt   = kk % 6;
    const int row0 = (xcd * 32 + kk / 6) * 128;
    const int nc0  = nt * 128;

    floatx4 acc[4][4];
#pragma unroll
    for (int i = 0; i < 4; i++)
#pragma unroll
        for (int j = 0; j < 4; j++) acc[i][j] = (floatx4){0.f, 0.f, 0.f, 0.f};

    const int arow  = (w << 5) + (lane >> 3);
    const int acolb = (lane & 7) << 3;
    const unsigned short* agp = xin + (size_t)(row0 + arow) * 256 + acolb;
    const unsigned short* bgp = wp  + (size_t)(nc0 + arow) * 256 + acolb;

    for (int c = 0; c < 4; ++c) {
        const int kb = c << 6;
#pragma unroll
        for (int p = 0; p < 4; ++p) {
            gl_lds16(agp + (size_t)(p * 8) * 256 + kb,
                     &lds.a[(w << 5) + (p << 3)][0]);
            gl_lds16(bgp + (size_t)(p * 8) * 256 + kb,
                     &lds.b[(w << 5) + (p << 3)][0]);
        }
        __syncthreads();
#pragma unroll
        for (int ks = 0; ks < 2; ++ks) {
            const int k8 = ks * 32 + lhi * 8;
            short8 a[4], b[4];
#pragma unroll
            for (int mi = 0; mi < 4; mi++)
                a[mi] = *(const short8*)&lds.a[wr * 64 + mi * 16 + llo][k8];
#pragma unroll
            for (int ni = 0; ni < 4; ni++)
                b[ni] = *(const short8*)&lds.b[wc * 64 + ni * 16 + llo][k8];
#pragma unroll
            for (int mi = 0; mi < 4; mi++)
#pragma unroll
                for (int ni = 0; ni < 4; ni++)
                    acc[mi][ni] = __builtin_amdgcn_mfma_f32_16x16x32_bf16(
                        a[mi], b[ni], acc[mi][ni], 0, 0, 0);
        }
        __syncthreads();
    }

    if (nt < 4) {
        const bool dev = (nt >= 2);
        float* obase = out + (dev ? DEV_OFF : (size_t)0);
        const int cb = (nt & 1) * 128 + wc * 64;
#pragma unroll
        for (int mi = 0; mi < 4; mi++)
#pragma unroll
            for (int ni = 0; ni < 4; ni++) {
                const int cc = cb + ni * 16 + llo;
#pragma unroll
                for (int r = 0; r < 4; r++) {
                    const int m = wr * 64 + mi * 16 + lhi * 4 + r;
                    float v = acc[mi][ni][r];
                    if (dev) v = __expf(v);
                    obase[(size_t)(row0 + m) * 256 + cc] = v;
                }
            }
    } else {
        // mult: lane owns t = (nt-4)*32 + wc*16 + llo; partners in ni
        const int t = (nt - 4) * 32 + wc * 16 + llo;
#pragma unroll
        for (int mi = 0; mi < 4; mi++)
#pragma unroll
            for (int r = 0; r < 4; r++) {
                const int mrow = wr * 64 + mi * 16 + lhi * 4 + r;
                float v0 = acc[mi][0][r], v1 = acc[mi][1][r];
                float v2 = acc[mi][2][r], v3 = acc[mi][3][r];
                float mx = fmaxf(fmaxf(v0, v1), fmaxf(v2, v3));
                float e0 = __expf(v0 - mx), e1 = __expf(v1 - mx);
                float e2 = __expf(v2 - mx), e3 = __expf(v3 - mx);
                float inv = 1.f / (e0 + e1 + e2 + e3);
                size_t base = MULT_OFF + (size_t)(row0 + mrow) * 256 + t;
                out[base]       = e0 * inv;
                out[base + 64]  = e1 * inv;
                out[base + 128] = e2 * inv;
                out[base + 192] = e3 * inv;
            }
    }
}

// ---------------------------------------------------------------------------
extern "C" void kernel_launch(void* const* d_in, const int* in_sizes, int n_in,
                              void* d_out, int out_size, void* d_ws, size_t ws_size,
                              hipStream_t stream)
{
    typedef const float* cfp;
    cfp inp = (cfp)d_in[0];
    cfp st1 = (cfp)d_in[1];
    cfp st2 = (cfp)d_in[2];
    cfp l1w0 = (cfp)d_in[3],  l1w1 = (cfp)d_in[7],  l1w2 = (cfp)d_in[11], l1w3 = (cfp)d_in[15];
    cfp l1b0 = (cfp)d_in[4],  l1b1 = (cfp)d_in[8],  l1b2 = (cfp)d_in[12], l1b3 = (cfp)d_in[16];
    cfp l2w0 = (cfp)d_in[5],  l2w1 = (cfp)d_in[9],  l2w2 = (cfp)d_in[13], l2w3 = (cfp)d_in[17];
    cfp l2b0 = (cfp)d_in[6],  l2b1 = (cfp)d_in[10], l2b2 = (cfp)d_in[14], l2b3 = (cfp)d_in[18];
    cfp ffw = (cfp)d_in[19];

    float* out = (float*)d_out;
    unsigned short* ws = (unsigned short*)d_ws;

    // pack + convert: 4,980,736 quad-element threads = 19456 blocks
    pack_all<<<19456, 256, 0, stream>>>(inp, st1, st2,
                                        l1w0, l1w1, l1w2, l1w3,
                                        l2w0, l2w1, l2w2, l2w3, ffw, ws);

    // layer 1: X1[B,320] @ W1p -> nstate1 (f32) + out1 bf16 -> X2 cols 0..255
    lstm_gemm<320, 512><<<2048, 256, 0, stream>>>(
        ws + X1O, ws + W1P, l1b0, l1b1, l1b2, l1b3,
        st1, out + NS1_OFF, ws + X2O);

    // layer 2: X2[B,512] @ W2p -> nstate2 (f32) + out2 bf16 -> X3
    lstm_gemm<512, 256><<<2048, 256, 0, stream>>>(
        ws + X2O, ws + W2P, l2b0, l2b1, l2b2, l2b3,
        st2, out + NS2_OFF, ws + X3O);

    // FF head + fused epilogues
    ff_gemm<<<1536, 256, 0, stream>>>(ws + X3O, ws + W3P, out);
}

// Round 3
// 493.075 us; speedup vs baseline: 1.1292x; 1.0267x over previous
//
#include <hip/hip_runtime.h>

// ============================================================================
// 2-layer LSTM cell + FF head, B=32768, IN=64, H=256, OUT=768.
//
// R5 = R4 + both-sides XOR chunk-swizzle on the GEMM LDS tiles.
//   LDS tile rows are 128 B (= exactly 32 banks) -> unswizzled fragment reads
//   are a 16-way bank conflict (16 llo-lanes read the same 16B column).
//   Swizzle: stored chunk c' = c ^ (row&7), realized as
//     - staging: linear LDS dest (global_load_lds requirement), per-lane
//       INVERSE-permuted global source column ((lane&7)^((lane>>3)&7))*16B
//       (row parity invariant across p: row blocks advance by 8)
//     - read: chunk = (ks*4+lhi) ^ (llo&7)
//   16-way -> 8-way (the floor for 128B-stride rows), ~2x cheaper ds_reads.
//
// R4 structure: m97-style GEMMs (128x128 tile, BK=64, 4 waves, global_load_lds
// width-16 both operands) over pre-converted bf16 activations, register-only
// epilogues (gate index packed into col bits [5:4]), XCD-aware block remap.
//
// d_in order: 0 inp 1 state1 2 state2 | 3 l1_wf 4 l1_bf 5 l2_wf 6 l2_bf
//  7 l1_wk 8 l1_bk 9 l2_wk 10 l2_bk | 11 l1_wi 12 l1_bi 13 l2_wi 14 l2_bi
// 15 l1_ws 16 l1_bs 17 l2_ws 18 l2_bs | 19 ff_w[256,768]  (all f32)
//
// d_out (f32): means[B,256] | dev[B,256] | mult[B,256] | ns1[B,512] | ns2[B,512]
// ============================================================================

typedef __attribute__((ext_vector_type(8))) short short8;    // 8 bf16
typedef __attribute__((ext_vector_type(4))) short short4_t;  // 4 bf16 = 8 B
typedef __attribute__((ext_vector_type(4))) float floatx4;   // MFMA acc

#define BATCH 32768

static const size_t DEV_OFF  = (size_t)BATCH * 256;
static const size_t MULT_OFF = (size_t)2 * BATCH * 256;
static const size_t NS1_OFF  = (size_t)3 * BATCH * 256;
static const size_t NS2_OFF  = NS1_OFF + (size_t)BATCH * 512;

// workspace layout (ushort elements)
static const size_t W1P = 0;                                 // [1024][320]
static const size_t W2P = (size_t)1024 * 320;                // [1024][512]
static const size_t W3P = W2P + (size_t)1024 * 512;          // [768][256]
static const size_t X1O = W3P + (size_t)768 * 256;           // [B][320]
static const size_t X2O = X1O + (size_t)BATCH * 320;         // [B][512]
static const size_t X3O = X2O + (size_t)BATCH * 512;         // [B][256]

__device__ __forceinline__ unsigned short f2bf(float f) {
    union { float f; unsigned int i; } v; v.f = f;
    unsigned int i = v.i;
    i += 0x7fff + ((i >> 16) & 1);   // RNE
    return (unsigned short)(i >> 16);
}
__device__ __forceinline__ float sigmoidf_(float x) {
    return 1.f / (1.f + __expf(-x));
}
__device__ __forceinline__ float tanhf_(float x) {
    float e = __expf(2.f * x);       // inf-safe: x>>0 -> 1, x<<0 -> -1
    return 1.f - 2.f / (e + 1.f);
}

// async global->LDS, 16 B per lane; LDS dest = wave-uniform base + lane*16
__device__ __forceinline__ void gl_lds16(const unsigned short* g,
                                         unsigned short* l) {
    __builtin_amdgcn_global_load_lds(
        (const __attribute__((address_space(1))) unsigned int*)g,
        (__attribute__((address_space(3))) unsigned int*)l,
        16, 0, 0);
}

// ---------------------------------------------------------------------------
// pack_all: X conversions (float4 -> bf16x4) + weight repack.
// thread q regions (exactly 19456*256 threads):
//   [0,524288)          inp        -> X1 cols 0..63
//   [524288,2621440)    s1.out     -> X1 cols 64..319
//   [2621440,4718592)   s2.out     -> X2 cols 256..511
//   [4718592,4800512)   W1 repack  (c = (h>>4)*64 + g*16 + (h&15))
//   [4800512,4931584)   W2 repack  (same col mapping)
//   [4931584,4980736)   W3 repack  (mult third: c = 512+(t>>4)*64+m*16+(t&15))
// ---------------------------------------------------------------------------
__global__ __launch_bounds__(256) void pack_all(
    const float* __restrict__ inp, const float* __restrict__ s1,
    const float* __restrict__ s2,
    const float* __restrict__ w10, const float* __restrict__ w11,
    const float* __restrict__ w12, const float* __restrict__ w13,
    const float* __restrict__ w20, const float* __restrict__ w21,
    const float* __restrict__ w22, const float* __restrict__ w23,
    const float* __restrict__ fw, unsigned short* __restrict__ ws)
{
    const int q = blockIdx.x * 256 + threadIdx.x;
    if (q < 524288) {
        int r = q >> 4, c = (q & 15) << 2;
        float4 v = *(const float4*)(inp + (size_t)r * 64 + c);
        short4_t h;
        h.x = (short)f2bf(v.x); h.y = (short)f2bf(v.y);
        h.z = (short)f2bf(v.z); h.w = (short)f2bf(v.w);
        *(short4_t*)(ws + X1O + (size_t)r * 320 + c) = h;
    } else if (q < 2621440) {
        int j = q - 524288;
        int r = j >> 6, c = (j & 63) << 2;
        float4 v = *(const float4*)(s1 + (size_t)r * 512 + c);
        short4_t h;
        h.x = (short)f2bf(v.x); h.y = (short)f2bf(v.y);
        h.z = (short)f2bf(v.z); h.w = (short)f2bf(v.w);
        *(short4_t*)(ws + X1O + (size_t)r * 320 + 64 + c) = h;
    } else if (q < 4718592) {
        int j = q - 2621440;
        int r = j >> 6, c = (j & 63) << 2;
        float4 v = *(const float4*)(s2 + (size_t)r * 512 + c);
        short4_t h;
        h.x = (short)f2bf(v.x); h.y = (short)f2bf(v.y);
        h.z = (short)f2bf(v.z); h.w = (short)f2bf(v.w);
        *(short4_t*)(ws + X2O + (size_t)r * 512 + 256 + c) = h;
    } else if (q < 4800512) {
        int j = q - 4718592;
        int n = j / 80, k = (j % 80) << 2;          // n = packed col
        int hh = ((n >> 6) << 4) + (n & 15);        // h
        int g = (n >> 4) & 3;                       // gate
        const float* s = g == 0 ? w10 : g == 1 ? w11 : g == 2 ? w12 : w13;
        short4_t o;
        o.x = (short)f2bf(s[(size_t)(k + 0) * 256 + hh]);
        o.y = (short)f2bf(s[(size_t)(k + 1) * 256 + hh]);
        o.z = (short)f2bf(s[(size_t)(k + 2) * 256 + hh]);
        o.w = (short)f2bf(s[(size_t)(k + 3) * 256 + hh]);
        *(short4_t*)(ws + W1P + (size_t)n * 320 + k) = o;
    } else if (q < 4931584) {
        int j = q - 4800512;
        int n = j >> 7, k = (j & 127) << 2;
        int hh = ((n >> 6) << 4) + (n & 15);
        int g = (n >> 4) & 3;
        const float* s = g == 0 ? w20 : g == 1 ? w21 : g == 2 ? w22 : w23;
        short4_t o;
        o.x = (short)f2bf(s[(size_t)(k + 0) * 256 + hh]);
        o.y = (short)f2bf(s[(size_t)(k + 1) * 256 + hh]);
        o.z = (short)f2bf(s[(size_t)(k + 2) * 256 + hh]);
        o.w = (short)f2bf(s[(size_t)(k + 3) * 256 + hh]);
        *(short4_t*)(ws + W2P + (size_t)n * 512 + k) = o;
    } else {
        int j = q - 4931584;
        int n = j >> 6, k = (j & 63) << 2;
        int col;
        if (n < 512) col = n;                       // means | deviances
        else {                                      // mult third, partner-in-ni
            int t = (((n - 512) >> 6) << 4) + (n & 15);
            int m = (n >> 4) & 3;
            col = 512 + m * 64 + t;
        }
        short4_t o;
        o.x = (short)f2bf(fw[(size_t)(k + 0) * 768 + col]);
        o.y = (short)f2bf(fw[(size_t)(k + 1) * 768 + col]);
        o.z = (short)f2bf(fw[(size_t)(k + 2) * 768 + col]);
        o.w = (short)f2bf(fw[(size_t)(k + 3) * 768 + col]);
        *(short4_t*)(ws + W3P + (size_t)n * 256 + k) = o;
    }
}

// ---------------------------------------------------------------------------
// LSTM GEMM+cell: 128x128 tile, BK=64, 4 waves (2x2 of 64x64), m97 staging,
// XOR chunk swizzle (stored chunk = global chunk ^ (row&7)).
// Grid 2048 1D, XCD-remapped. Lane owns gates f,k,i,s of h = nt*32+wc*16+llo
// in acc[mi][0..3][r]; register-only cell update.
// ---------------------------------------------------------------------------
template<int KT, int XST>
__global__ __launch_bounds__(256) void lstm_gemm(
    const unsigned short* __restrict__ xin,   // [B][KT] bf16
    const unsigned short* __restrict__ wp,    // [1024][KT] bf16 packed cols
    const float* __restrict__ b0, const float* __restrict__ b1,
    const float* __restrict__ b2, const float* __restrict__ b3,
    const float* __restrict__ state,          // [B][512] f32 (cell at +256)
    float* __restrict__ nstate,               // [B][512] f32
    unsigned short* __restrict__ xnext)       // [B][XST] bf16, cols 0..255
{
    __shared__ __align__(16) struct {
        unsigned short a[128][64];
        unsigned short b[128][64];
    } lds;

    const int tid  = threadIdx.x;
    const int w    = tid >> 6;
    const int lane = tid & 63;
    const int lhi  = lane >> 4, llo = lane & 15;
    const int wr   = w >> 1, wc = w & 1;

    // XCD-aware remap: same A-tile consumed by 8 consecutive same-XCD blocks
    const int lin  = blockIdx.x;
    const int xcd  = lin & 7;
    const int kk   = lin >> 3;
    const int nt   = kk & 7;
    const int row0 = (xcd * 32 + (kk >> 3)) * 128;
    const int nc0  = nt * 128;

    // bias hoist (lane owns h = nt*32 + wc*16 + llo)
    const int h = nt * 32 + wc * 16 + llo;
    const float bf_ = b0[h], bk_ = b1[h], bi_ = b2[h], bs_ = b3[h];

    floatx4 acc[4][4];
#pragma unroll
    for (int i = 0; i < 4; i++)
#pragma unroll
        for (int j = 0; j < 4; j++) acc[i][j] = (floatx4){0.f, 0.f, 0.f, 0.f};

    const int arow  = (w << 5) + (lane >> 3);     // wave stages 32 rows
    // inverse-swizzled source column: stored chunk (lane&7) gets global
    // chunk (lane&7)^(row&7); row&7 = (lane>>3)&7, invariant across p (+8 rows)
    const int acolb = (((lane & 7) ^ ((lane >> 3) & 7)) << 3);  // ushort off
    const unsigned short* agp = xin + (size_t)(row0 + arow) * KT + acolb;
    const unsigned short* bgp = wp  + (size_t)(nc0 + arow) * KT + acolb;

    // swizzled read chunk offsets (ushort): chunk = (ks*4+lhi) ^ (llo&7)
    const int sx  = llo & 7;
    const int kq0 = ((lhi ^ sx) << 3);
    const int kq1 = (((4 | lhi) ^ sx) << 3);

    for (int c = 0; c < KT / 64; ++c) {
        const int kb = c << 6;
#pragma unroll
        for (int p = 0; p < 4; ++p) {
            gl_lds16(agp + (size_t)(p * 8) * KT + kb,
                     &lds.a[(w << 5) + (p << 3)][0]);
            gl_lds16(bgp + (size_t)(p * 8) * KT + kb,
                     &lds.b[(w << 5) + (p << 3)][0]);
        }
        __syncthreads();
#pragma unroll
        for (int ks = 0; ks < 2; ++ks) {
            const int kq = ks ? kq1 : kq0;
            short8 a[4], b[4];
#pragma unroll
            for (int mi = 0; mi < 4; mi++)
                a[mi] = *(const short8*)&lds.a[wr * 64 + mi * 16 + llo][kq];
#pragma unroll
            for (int ni = 0; ni < 4; ni++)
                b[ni] = *(const short8*)&lds.b[wc * 64 + ni * 16 + llo][kq];
#pragma unroll
            for (int mi = 0; mi < 4; mi++)
#pragma unroll
                for (int ni = 0; ni < 4; ni++)
                    acc[mi][ni] = __builtin_amdgcn_mfma_f32_16x16x32_bf16(
                        a[mi], b[ni], acc[mi][ni], 0, 0, 0);
        }
        __syncthreads();
    }

    // ---- register-only cell update ----
#pragma unroll
    for (int mi = 0; mi < 4; mi++)
#pragma unroll
        for (int r = 0; r < 4; r++) {
            const int m = wr * 64 + mi * 16 + lhi * 4 + r;
            const size_t rowel = (size_t)(row0 + m) * 512;
            float rst = sigmoidf_(acc[mi][0][r] + bf_);
            float wrt = sigmoidf_(acc[mi][1][r] + bk_);
            float itm = tanhf_(acc[mi][2][r] + bi_);
            float rd  = sigmoidf_(acc[mi][3][r] + bs_);
            float cold = state[rowel + 256 + h];
            float cell = rst * cold + wrt * itm;
            float o = rd * tanhf_(cell);
            nstate[rowel + h]       = o;
            nstate[rowel + 256 + h] = cell;
            xnext[(size_t)(row0 + m) * XST + h] = f2bf(o);
        }
}

// ---------------------------------------------------------------------------
// FF head GEMM: X3[B,256] @ W3p[768,256]; grid 1536 1D, XCD-remapped,
// XOR chunk swizzle.  nt 0,1 -> means; nt 2,3 -> exp(dev);
// nt 4,5 -> mult (softmax partners in ni dimension, register-only).
// ---------------------------------------------------------------------------
__global__ __launch_bounds__(256) void ff_gemm(
    const unsigned short* __restrict__ xin,   // [B][256] bf16
    const unsigned short* __restrict__ wp,    // [768][256] bf16 packed
    float* __restrict__ out)
{
    __shared__ __align__(16) struct {
        unsigned short a[128][64];
        unsigned short b[128][64];
    } lds;

    const int tid  = threadIdx.x;
    const int w    = tid >> 6;
    const int lane = tid & 63;
    const int lhi  = lane >> 4, llo = lane & 15;
    const int wr   = w >> 1, wc = w & 1;

    const int lin  = blockIdx.x;
    const int xcd  = lin & 7;
    const int kk   = lin >> 3;                // [0,192)
    const int nt   = kk % 6;
    const int row0 = (xcd * 32 + kk / 6) * 128;
    const int nc0  = nt * 128;

    floatx4 acc[4][4];
#pragma unroll
    for (int i = 0; i < 4; i++)
#pragma unroll
        for (int j = 0; j < 4; j++) acc[i][j] = (floatx4){0.f, 0.f, 0.f, 0.f};

    const int arow  = (w << 5) + (lane >> 3);
    const int acolb = (((lane & 7) ^ ((lane >> 3) & 7)) << 3);
    const unsigned short* agp = xin + (size_t)(row0 + arow) * 256 + acolb;
    const unsigned short* bgp = wp  + (size_t)(nc0 + arow) * 256 + acolb;

    const int sx  = llo & 7;
    const int kq0 = ((lhi ^ sx) << 3);
    const int kq1 = (((4 | lhi) ^ sx) << 3);

    for (int c = 0; c < 4; ++c) {
        const int kb = c << 6;
#pragma unroll
        for (int p = 0; p < 4; ++p) {
            gl_lds16(agp + (size_t)(p * 8) * 256 + kb,
                     &lds.a[(w << 5) + (p << 3)][0]);
            gl_lds16(bgp + (size_t)(p * 8) * 256 + kb,
                     &lds.b[(w << 5) + (p << 3)][0]);
        }
        __syncthreads();
#pragma unroll
        for (int ks = 0; ks < 2; ++ks) {
            const int kq = ks ? kq1 : kq0;
            short8 a[4], b[4];
#pragma unroll
            for (int mi = 0; mi < 4; mi++)
                a[mi] = *(const short8*)&lds.a[wr * 64 + mi * 16 + llo][kq];
#pragma unroll
            for (int ni = 0; ni < 4; ni++)
                b[ni] = *(const short8*)&lds.b[wc * 64 + ni * 16 + llo][kq];
#pragma unroll
            for (int mi = 0; mi < 4; mi++)
#pragma unroll
                for (int ni = 0; ni < 4; ni++)
                    acc[mi][ni] = __builtin_amdgcn_mfma_f32_16x16x32_bf16(
                        a[mi], b[ni], acc[mi][ni], 0, 0, 0);
        }
        __syncthreads();
    }

    if (nt < 4) {
        const bool dev = (nt >= 2);
        float* obase = out + (dev ? DEV_OFF : (size_t)0);
        const int cb = (nt & 1) * 128 + wc * 64;
#pragma unroll
        for (int mi = 0; mi < 4; mi++)
#pragma unroll
            for (int ni = 0; ni < 4; ni++) {
                const int cc = cb + ni * 16 + llo;
#pragma unroll
                for (int r = 0; r < 4; r++) {
                    const int m = wr * 64 + mi * 16 + lhi * 4 + r;
                    float v = acc[mi][ni][r];
                    if (dev) v = __expf(v);
                    obase[(size_t)(row0 + m) * 256 + cc] = v;
                }
            }
    } else {
        // mult: lane owns t = (nt-4)*32 + wc*16 + llo; partners in ni
        const int t = (nt - 4) * 32 + wc * 16 + llo;
#pragma unroll
        for (int mi = 0; mi < 4; mi++)
#pragma unroll
            for (int r = 0; r < 4; r++) {
                const int mrow = wr * 64 + mi * 16 + lhi * 4 + r;
                float v0 = acc[mi][0][r], v1 = acc[mi][1][r];
                float v2 = acc[mi][2][r], v3 = acc[mi][3][r];
                float mx = fmaxf(fmaxf(v0, v1), fmaxf(v2, v3));
                float e0 = __expf(v0 - mx), e1 = __expf(v1 - mx);
                float e2 = __expf(v2 - mx), e3 = __expf(v3 - mx);
                float inv = 1.f / (e0 + e1 + e2 + e3);
                size_t base = MULT_OFF + (size_t)(row0 + mrow) * 256 + t;
                out[base]       = e0 * inv;
                out[base + 64]  = e1 * inv;
                out[base + 128] = e2 * inv;
                out[base + 192] = e3 * inv;
            }
    }
}

// ---------------------------------------------------------------------------
extern "C" void kernel_launch(void* const* d_in, const int* in_sizes, int n_in,
                              void* d_out, int out_size, void* d_ws, size_t ws_size,
                              hipStream_t stream)
{
    typedef const float* cfp;
    cfp inp = (cfp)d_in[0];
    cfp st1 = (cfp)d_in[1];
    cfp st2 = (cfp)d_in[2];
    cfp l1w0 = (cfp)d_in[3],  l1w1 = (cfp)d_in[7],  l1w2 = (cfp)d_in[11], l1w3 = (cfp)d_in[15];
    cfp l1b0 = (cfp)d_in[4],  l1b1 = (cfp)d_in[8],  l1b2 = (cfp)d_in[12], l1b3 = (cfp)d_in[16];
    cfp l2w0 = (cfp)d_in[5],  l2w1 = (cfp)d_in[9],  l2w2 = (cfp)d_in[13], l2w3 = (cfp)d_in[17];
    cfp l2b0 = (cfp)d_in[6],  l2b1 = (cfp)d_in[10], l2b2 = (cfp)d_in[14], l2b3 = (cfp)d_in[18];
    cfp ffw = (cfp)d_in[19];

    float* out = (float*)d_out;
    unsigned short* ws = (unsigned short*)d_ws;

    // pack + convert: 4,980,736 quad-element threads = 19456 blocks
    pack_all<<<19456, 256, 0, stream>>>(inp, st1, st2,
                                        l1w0, l1w1, l1w2, l1w3,
                                        l2w0, l2w1, l2w2, l2w3, ffw, ws);

    // layer 1: X1[B,320] @ W1p -> nstate1 (f32) + out1 bf16 -> X2 cols 0..255
    lstm_gemm<320, 512><<<2048, 256, 0, stream>>>(
        ws + X1O, ws + W1P, l1b0, l1b1, l1b2, l1b3,
        st1, out + NS1_OFF, ws + X2O);

    // layer 2: X2[B,512] @ W2p -> nstate2 (f32) + out2 bf16 -> X3
    lstm_gemm<512, 256><<<2048, 256, 0, stream>>>(
        ws + X2O, ws + W2P, l2b0, l2b1, l2b2, l2b3,
        st2, out + NS2_OFF, ws + X3O);

    // FF head + fused epilogues
    ff_gemm<<<1536, 256, 0, stream>>>(ws + X3O, ws + W3P, out);
}

// Round 4
// 480.733 us; speedup vs baseline: 1.1582x; 1.0257x over previous
//
#include <hip/hip_runtime.h>

// ============================================================================
// 2-layer LSTM cell + FF head, B=32768, IN=64, H=256, OUT=768.
//
// R6 = R5 + pack split/overlap:
//   - pack1 (serial, small): inp + state1.out -> X1 bf16, W1 repack (~70 MB).
//   - pack2 work (state2.out -> X2 high half, W2, W3 repack, ~90 MB) is
//     folded into lstm1's grid as 2224 trailing WORKER blocks -> overlaps
//     with lstm1's MFMA phase instead of serializing in front of the chain.
//     (lstm2/ff only need this data after lstm1 completes: kernel-boundary
//      dependency, no extra sync needed.)
//   - __launch_bounds__(256,4) on GEMM kernels: cap VGPR at 128 so blocks/CU
//     never drops to 3.
//
// R5: both-sides XOR chunk swizzle on GEMM LDS tiles (16-way -> 8-way floor).
// R4: m97 GEMMs (128x128, BK=64, global_load_lds x16 both operands),
//     register-only epilogues (gate packed in col bits [5:4]), XCD remap.
//
// d_in order: 0 inp 1 state1 2 state2 | 3 l1_wf 4 l1_bf 5 l2_wf 6 l2_bf
//  7 l1_wk 8 l1_bk 9 l2_wk 10 l2_bk | 11 l1_wi 12 l1_bi 13 l2_wi 14 l2_bi
// 15 l1_ws 16 l1_bs 17 l2_ws 18 l2_bs | 19 ff_w[256,768]  (all f32)
//
// d_out (f32): means[B,256] | dev[B,256] | mult[B,256] | ns1[B,512] | ns2[B,512]
// ============================================================================

typedef __attribute__((ext_vector_type(8))) short short8;    // 8 bf16
typedef __attribute__((ext_vector_type(4))) short short4_t;  // 4 bf16 = 8 B
typedef __attribute__((ext_vector_type(4))) float floatx4;   // MFMA acc

#define BATCH 32768

static const size_t DEV_OFF  = (size_t)BATCH * 256;
static const size_t MULT_OFF = (size_t)2 * BATCH * 256;
static const size_t NS1_OFF  = (size_t)3 * BATCH * 256;
static const size_t NS2_OFF  = NS1_OFF + (size_t)BATCH * 512;

// workspace layout (ushort elements)
static const size_t W1P = 0;                                 // [1024][320]
static const size_t W2P = (size_t)1024 * 320;                // [1024][512]
static const size_t W3P = W2P + (size_t)1024 * 512;          // [768][256]
static const size_t X1O = W3P + (size_t)768 * 256;           // [B][320]
static const size_t X2O = X1O + (size_t)BATCH * 320;         // [B][512]
static const size_t X3O = X2O + (size_t)BATCH * 512;         // [B][256]

__device__ __forceinline__ unsigned short f2bf(float f) {
    union { float f; unsigned int i; } v; v.f = f;
    unsigned int i = v.i;
    i += 0x7fff + ((i >> 16) & 1);   // RNE
    return (unsigned short)(i >> 16);
}
__device__ __forceinline__ float sigmoidf_(float x) {
    return 1.f / (1.f + __expf(-x));
}
__device__ __forceinline__ float tanhf_(float x) {
    float e = __expf(2.f * x);       // inf-safe: x>>0 -> 1, x<<0 -> -1
    return 1.f - 2.f / (e + 1.f);
}

// async global->LDS, 16 B per lane; LDS dest = wave-uniform base + lane*16
__device__ __forceinline__ void gl_lds16(const unsigned short* g,
                                         unsigned short* l) {
    __builtin_amdgcn_global_load_lds(
        (const __attribute__((address_space(1))) unsigned int*)g,
        (__attribute__((address_space(3))) unsigned int*)l,
        16, 0, 0);
}

// ---------------------------------------------------------------------------
// pack1: only what lstm1 needs up front.
// quad index space (each quad = 4 f32 -> 4 bf16):
//   [0,524288)          inp     -> X1 cols 0..63
//   [524288,2621440)    s1.out  -> X1 cols 64..319
//   [2621440,2703360)   W1 repack (c = (h>>4)*64 + g*16 + (h&15))
// 2640 blocks x 256 thr x 4 quads = 2,703,360 quads exactly.
// ---------------------------------------------------------------------------
__global__ __launch_bounds__(256) void pack1(
    const float* __restrict__ inp, const float* __restrict__ s1,
    const float* __restrict__ w10, const float* __restrict__ w11,
    const float* __restrict__ w12, const float* __restrict__ w13,
    unsigned short* __restrict__ ws)
{
    const int wt = blockIdx.x * 256 + threadIdx.x;   // 0..675839
#pragma unroll
    for (int j = 0; j < 4; ++j) {
        const int q = wt + j * 675840;
        if (q < 524288) {
            int r = q >> 4, c = (q & 15) << 2;
            float4 v = *(const float4*)(inp + (size_t)r * 64 + c);
            short4_t h;
            h.x = (short)f2bf(v.x); h.y = (short)f2bf(v.y);
            h.z = (short)f2bf(v.z); h.w = (short)f2bf(v.w);
            *(short4_t*)(ws + X1O + (size_t)r * 320 + c) = h;
        } else if (q < 2621440) {
            int jj = q - 524288;
            int r = jj >> 6, c = (jj & 63) << 2;
            float4 v = *(const float4*)(s1 + (size_t)r * 512 + c);
            short4_t h;
            h.x = (short)f2bf(v.x); h.y = (short)f2bf(v.y);
            h.z = (short)f2bf(v.z); h.w = (short)f2bf(v.w);
            *(short4_t*)(ws + X1O + (size_t)r * 320 + 64 + c) = h;
        } else {
            int jj = q - 2621440;
            int n = jj / 80, k = (jj % 80) << 2;     // n = packed col
            int hh = ((n >> 6) << 4) + (n & 15);     // h
            int g = (n >> 4) & 3;                    // gate
            const float* s = g == 0 ? w10 : g == 1 ? w11 : g == 2 ? w12 : w13;
            short4_t o;
            o.x = (short)f2bf(s[(size_t)(k + 0) * 256 + hh]);
            o.y = (short)f2bf(s[(size_t)(k + 1) * 256 + hh]);
            o.z = (short)f2bf(s[(size_t)(k + 2) * 256 + hh]);
            o.w = (short)f2bf(s[(size_t)(k + 3) * 256 + hh]);
            *(short4_t*)(ws + W1P + (size_t)n * 320 + k) = o;
        }
    }
}

// ---------------------------------------------------------------------------
// LSTM GEMM+cell: 128x128 tile, BK=64, 4 waves, m97 staging, XOR chunk
// swizzle (stored chunk = global chunk ^ (row&7)), XCD-aware remap.
// Lane owns gates f,k,i,s of h = nt*32+wc*16+llo in acc[mi][0..3][r];
// register-only cell update.
// PACK=true (layer 1): blocks lin >= 2048 are pure-memory workers doing the
// deferred pack work (s2.out -> X2 cols 256..511, W2 repack, W3 repack);
// they overlap with the GEMM blocks and complete before kernel end.
//   worker quad space: [0,2097152) s2 | [2097152,2228224) W2 | [..,2277376) W3
//   2224 blocks x 256 thr x 4 quads = 2,277,376 exactly.
// ---------------------------------------------------------------------------
template<int KT, int XST, bool PACK>
__global__ __launch_bounds__(256, 4) void lstm_gemm(
    const unsigned short* __restrict__ xin,   // [B][KT] bf16
    const unsigned short* __restrict__ wp,    // [1024][KT] bf16 packed cols
    const float* __restrict__ b0, const float* __restrict__ b1,
    const float* __restrict__ b2, const float* __restrict__ b3,
    const float* __restrict__ state,          // [B][512] f32 (cell at +256)
    float* __restrict__ nstate,               // [B][512] f32
    unsigned short* __restrict__ xnext,       // [B][XST] bf16, cols 0..255
    const float* __restrict__ s2f,            // worker: state2 f32 (or null)
    const float* __restrict__ w20, const float* __restrict__ w21,
    const float* __restrict__ w22, const float* __restrict__ w23,
    const float* __restrict__ fw,             // worker: ff_w (or null)
    unsigned short* __restrict__ wsbase)      // worker: ws base (or null)
{
    const int tid = threadIdx.x;
    const int lin = blockIdx.x;

    if (PACK && lin >= 2048) {
        // ---------------- deferred-pack worker block ----------------
        const int wt = (lin - 2048) * 256 + tid;     // 0..569343
#pragma unroll
        for (int j = 0; j < 4; ++j) {
            const int q = wt + j * 569344;
            if (q < 2097152) {                        // s2.out -> X2 high half
                int r = q >> 6, c = (q & 63) << 2;
                float4 v = *(const float4*)(s2f + (size_t)r * 512 + c);
                short4_t h;
                h.x = (short)f2bf(v.x); h.y = (short)f2bf(v.y);
                h.z = (short)f2bf(v.z); h.w = (short)f2bf(v.w);
                *(short4_t*)(wsbase + X2O + (size_t)r * 512 + 256 + c) = h;
            } else if (q < 2228224) {                 // W2 repack
                int jj = q - 2097152;
                int n = jj >> 7, k = (jj & 127) << 2;
                int hh = ((n >> 6) << 4) + (n & 15);
                int g = (n >> 4) & 3;
                const float* s = g == 0 ? w20 : g == 1 ? w21
                               : g == 2 ? w22 : w23;
                short4_t o;
                o.x = (short)f2bf(s[(size_t)(k + 0) * 256 + hh]);
                o.y = (short)f2bf(s[(size_t)(k + 1) * 256 + hh]);
                o.z = (short)f2bf(s[(size_t)(k + 2) * 256 + hh]);
                o.w = (short)f2bf(s[(size_t)(k + 3) * 256 + hh]);
                *(short4_t*)(wsbase + W2P + (size_t)n * 512 + k) = o;
            } else {                                  // W3 repack
                int jj = q - 2228224;
                int n = jj >> 6, k = (jj & 63) << 2;
                int col;
                if (n < 512) col = n;                 // means | deviances
                else {                                // mult third, partner-in-ni
                    int t = (((n - 512) >> 6) << 4) + (n & 15);
                    int m = (n >> 4) & 3;
                    col = 512 + m * 64 + t;
                }
                short4_t o;
                o.x = (short)f2bf(fw[(size_t)(k + 0) * 768 + col]);
                o.y = (short)f2bf(fw[(size_t)(k + 1) * 768 + col]);
                o.z = (short)f2bf(fw[(size_t)(k + 2) * 768 + col]);
                o.w = (short)f2bf(fw[(size_t)(k + 3) * 768 + col]);
                *(short4_t*)(wsbase + W3P + (size_t)n * 256 + k) = o;
            }
        }
        return;
    }

    // ---------------- GEMM + fused cell update ----------------
    __shared__ __align__(16) struct {
        unsigned short a[128][64];
        unsigned short b[128][64];
    } lds;

    const int w    = tid >> 6;
    const int lane = tid & 63;
    const int lhi  = lane >> 4, llo = lane & 15;
    const int wr   = w >> 1, wc = w & 1;

    // XCD-aware remap: same A-tile consumed by 8 consecutive same-XCD blocks
    const int xcd  = lin & 7;
    const int kk   = lin >> 3;
    const int nt   = kk & 7;
    const int row0 = (xcd * 32 + (kk >> 3)) * 128;
    const int nc0  = nt * 128;

    // bias hoist (lane owns h = nt*32 + wc*16 + llo)
    const int h = nt * 32 + wc * 16 + llo;
    const float bf_ = b0[h], bk_ = b1[h], bi_ = b2[h], bs_ = b3[h];

    floatx4 acc[4][4];
#pragma unroll
    for (int i = 0; i < 4; i++)
#pragma unroll
        for (int j = 0; j < 4; j++) acc[i][j] = (floatx4){0.f, 0.f, 0.f, 0.f};

    const int arow  = (w << 5) + (lane >> 3);     // wave stages 32 rows
    // inverse-swizzled source column: stored chunk (lane&7) gets global
    // chunk (lane&7)^(row&7); row&7 = (lane>>3)&7, invariant across p (+8 rows)
    const int acolb = (((lane & 7) ^ ((lane >> 3) & 7)) << 3);  // ushort off
    const unsigned short* agp = xin + (size_t)(row0 + arow) * KT + acolb;
    const unsigned short* bgp = wp  + (size_t)(nc0 + arow) * KT + acolb;

    // swizzled read chunk offsets (ushort): chunk = (ks*4+lhi) ^ (llo&7)
    const int sx  = llo & 7;
    const int kq0 = ((lhi ^ sx) << 3);
    const int kq1 = (((4 | lhi) ^ sx) << 3);

    for (int c = 0; c < KT / 64; ++c) {
        const int kb = c << 6;
#pragma unroll
        for (int p = 0; p < 4; ++p) {
            gl_lds16(agp + (size_t)(p * 8) * KT + kb,
                     &lds.a[(w << 5) + (p << 3)][0]);
            gl_lds16(bgp + (size_t)(p * 8) * KT + kb,
                     &lds.b[(w << 5) + (p << 3)][0]);
        }
        __syncthreads();
#pragma unroll
        for (int ks = 0; ks < 2; ++ks) {
            const int kq = ks ? kq1 : kq0;
            short8 a[4], b[4];
#pragma unroll
            for (int mi = 0; mi < 4; mi++)
                a[mi] = *(const short8*)&lds.a[wr * 64 + mi * 16 + llo][kq];
#pragma unroll
            for (int ni = 0; ni < 4; ni++)
                b[ni] = *(const short8*)&lds.b[wc * 64 + ni * 16 + llo][kq];
#pragma unroll
            for (int mi = 0; mi < 4; mi++)
#pragma unroll
                for (int ni = 0; ni < 4; ni++)
                    acc[mi][ni] = __builtin_amdgcn_mfma_f32_16x16x32_bf16(
                        a[mi], b[ni], acc[mi][ni], 0, 0, 0);
        }
        __syncthreads();
    }

    // ---- register-only cell update ----
#pragma unroll
    for (int mi = 0; mi < 4; mi++)
#pragma unroll
        for (int r = 0; r < 4; r++) {
            const int m = wr * 64 + mi * 16 + lhi * 4 + r;
            const size_t rowel = (size_t)(row0 + m) * 512;
            float rst = sigmoidf_(acc[mi][0][r] + bf_);
            float wrt = sigmoidf_(acc[mi][1][r] + bk_);
            float itm = tanhf_(acc[mi][2][r] + bi_);
            float rd  = sigmoidf_(acc[mi][3][r] + bs_);
            float cold = state[rowel + 256 + h];
            float cell = rst * cold + wrt * itm;
            float o = rd * tanhf_(cell);
            nstate[rowel + h]       = o;
            nstate[rowel + 256 + h] = cell;
            xnext[(size_t)(row0 + m) * XST + h] = f2bf(o);
        }
}

// ---------------------------------------------------------------------------
// FF head GEMM: X3[B,256] @ W3p[768,256]; grid 1536 1D, XCD-remapped,
// XOR chunk swizzle.  nt 0,1 -> means; nt 2,3 -> exp(dev);
// nt 4,5 -> mult (softmax partners in ni dimension, register-only).
// ---------------------------------------------------------------------------
__global__ __launch_bounds__(256, 4) void ff_gemm(
    const unsigned short* __restrict__ xin,   // [B][256] bf16
    const unsigned short* __restrict__ wp,    // [768][256] bf16 packed
    float* __restrict__ out)
{
    __shared__ __align__(16) struct {
        unsigned short a[128][64];
        unsigned short b[128][64];
    } lds;

    const int tid  = threadIdx.x;
    const int w    = tid >> 6;
    const int lane = tid & 63;
    const int lhi  = lane >> 4, llo = lane & 15;
    const int wr   = w >> 1, wc = w & 1;

    const int lin  = blockIdx.x;
    const int xcd  = lin & 7;
    const int kk   = lin >> 3;                // [0,192)
    const int nt   = kk % 6;
    const int row0 = (xcd * 32 + kk / 6) * 128;
    const int nc0  = nt * 128;

    floatx4 acc[4][4];
#pragma unroll
    for (int i = 0; i < 4; i++)
#pragma unroll
        for (int j = 0; j < 4; j++) acc[i][j] = (floatx4){0.f, 0.f, 0.f, 0.f};

    const int arow  = (w << 5) + (lane >> 3);
    const int acolb = (((lane & 7) ^ ((lane >> 3) & 7)) << 3);
    const unsigned short* agp = xin + (size_t)(row0 + arow) * 256 + acolb;
    const unsigned short* bgp = wp  + (size_t)(nc0 + arow) * 256 + acolb;

    const int sx  = llo & 7;
    const int kq0 = ((lhi ^ sx) << 3);
    const int kq1 = (((4 | lhi) ^ sx) << 3);

    for (int c = 0; c < 4; ++c) {
        const int kb = c << 6;
#pragma unroll
        for (int p = 0; p < 4; ++p) {
            gl_lds16(agp + (size_t)(p * 8) * 256 + kb,
                     &lds.a[(w << 5) + (p << 3)][0]);
            gl_lds16(bgp + (size_t)(p * 8) * 256 + kb,
                     &lds.b[(w << 5) + (p << 3)][0]);
        }
        __syncthreads();
#pragma unroll
        for (int ks = 0; ks < 2; ++ks) {
            const int kq = ks ? kq1 : kq0;
            short8 a[4], b[4];
#pragma unroll
            for (int mi = 0; mi < 4; mi++)
                a[mi] = *(const short8*)&lds.a[wr * 64 + mi * 16 + llo][kq];
#pragma unroll
            for (int ni = 0; ni < 4; ni++)
                b[ni] = *(const short8*)&lds.b[wc * 64 + ni * 16 + llo][kq];
#pragma unroll
            for (int mi = 0; mi < 4; mi++)
#pragma unroll
                for (int ni = 0; ni < 4; ni++)
                    acc[mi][ni] = __builtin_amdgcn_mfma_f32_16x16x32_bf16(
                        a[mi], b[ni], acc[mi][ni], 0, 0, 0);
        }
        __syncthreads();
    }

    if (nt < 4) {
        const bool dev = (nt >= 2);
        float* obase = out + (dev ? DEV_OFF : (size_t)0);
        const int cb = (nt & 1) * 128 + wc * 64;
#pragma unroll
        for (int mi = 0; mi < 4; mi++)
#pragma unroll
            for (int ni = 0; ni < 4; ni++) {
                const int cc = cb + ni * 16 + llo;
#pragma unroll
                for (int r = 0; r < 4; r++) {
                    const int m = wr * 64 + mi * 16 + lhi * 4 + r;
                    float v = acc[mi][ni][r];
                    if (dev) v = __expf(v);
                    obase[(size_t)(row0 + m) * 256 + cc] = v;
                }
            }
    } else {
        // mult: lane owns t = (nt-4)*32 + wc*16 + llo; partners in ni
        const int t = (nt - 4) * 32 + wc * 16 + llo;
#pragma unroll
        for (int mi = 0; mi < 4; mi++)
#pragma unroll
            for (int r = 0; r < 4; r++) {
                const int mrow = wr * 64 + mi * 16 + lhi * 4 + r;
                float v0 = acc[mi][0][r], v1 = acc[mi][1][r];
                float v2 = acc[mi][2][r], v3 = acc[mi][3][r];
                float mx = fmaxf(fmaxf(v0, v1), fmaxf(v2, v3));
                float e0 = __expf(v0 - mx), e1 = __expf(v1 - mx);
                float e2 = __expf(v2 - mx), e3 = __expf(v3 - mx);
                float inv = 1.f / (e0 + e1 + e2 + e3);
                size_t base = MULT_OFF + (size_t)(row0 + mrow) * 256 + t;
                out[base]       = e0 * inv;
                out[base + 64]  = e1 * inv;
                out[base + 128] = e2 * inv;
                out[base + 192] = e3 * inv;
            }
    }
}

// ---------------------------------------------------------------------------
extern "C" void kernel_launch(void* const* d_in, const int* in_sizes, int n_in,
                              void* d_out, int out_size, void* d_ws, size_t ws_size,
                              hipStream_t stream)
{
    typedef const float* cfp;
    cfp inp = (cfp)d_in[0];
    cfp st1 = (cfp)d_in[1];
    cfp st2 = (cfp)d_in[2];
    cfp l1w0 = (cfp)d_in[3],  l1w1 = (cfp)d_in[7],  l1w2 = (cfp)d_in[11], l1w3 = (cfp)d_in[15];
    cfp l1b0 = (cfp)d_in[4],  l1b1 = (cfp)d_in[8],  l1b2 = (cfp)d_in[12], l1b3 = (cfp)d_in[16];
    cfp l2w0 = (cfp)d_in[5],  l2w1 = (cfp)d_in[9],  l2w2 = (cfp)d_in[13], l2w3 = (cfp)d_in[17];
    cfp l2b0 = (cfp)d_in[6],  l2b1 = (cfp)d_in[10], l2b2 = (cfp)d_in[14], l2b3 = (cfp)d_in[18];
    cfp ffw = (cfp)d_in[19];

    float* out = (float*)d_out;
    unsigned short* ws = (unsigned short*)d_ws;

    // pack1: X1 + W1 only (2,703,360 quads = 2640 blocks x 256 x 4)
    pack1<<<2640, 256, 0, stream>>>(inp, st1, l1w0, l1w1, l1w2, l1w3, ws);

    // layer 1 + deferred pack workers (s2->X2 high, W2, W3):
    //   2048 GEMM blocks + 2224 worker blocks
    lstm_gemm<320, 512, true><<<4272, 256, 0, stream>>>(
        ws + X1O, ws + W1P, l1b0, l1b1, l1b2, l1b3,
        st1, out + NS1_OFF, ws + X2O,
        st2, l2w0, l2w1, l2w2, l2w3, ffw, ws);

    // layer 2: X2[B,512] @ W2p -> nstate2 (f32) + out2 bf16 -> X3
    lstm_gemm<512, 256, false><<<2048, 256, 0, stream>>>(
        ws + X2O, ws + W2P, l2b0, l2b1, l2b2, l2b3,
        st2, out + NS2_OFF, ws + X3O,
        nullptr, nullptr, nullptr, nullptr, nullptr, nullptr, nullptr);

    // FF head + fused epilogues
    ff_gemm<<<1536, 256, 0, stream>>>(ws + X3O, ws + W3P, out);
}